// Round 5
// baseline (118.578 us; speedup 1.0000x reference)
//
#include <hip/hip_runtime.h>
#include <hip/hip_bf16.h>
#include <math.h>

// AdditiveAttention: B=4, Q=512, K=512, H=256, fp32.
// scores[b,q,k] = sum_h wv_h * tanh(qp + kp) -> softmax_k -> @V
// tanh(x) = 1 - 2/(1+e^{2x}); sum_h wv_h drops out of softmax.
// e^{2(q+k)} = e^{2q} * e^{2k}: exponentiate projections once (proj kernel).
// 4 h-terms share one rcp: sum wv_i/t_i = num/(t0*t1*t2*t3).
//
// R4 lesson: grid-barrier fusion => cross-XCD coherence storm. Two launches.
// R6 lesson: full unroll + reg prefetch + VGPR<=64 cap => scratch spill storm
//            (FETCH 410MB). Keep runtime loop + shallow prefetch.
// R8 lesson: 4q-acc + deep prefetch in P3 (48+ live regs vs the 32-reg budget
//            this compiler pins under launch_bounds(1024,8)) => spill storm
//            (WRITE 381MB, 160us). P3 live state MUST stay <= ~26 regs.
// R9: P3 q-pair sharing one V stream: V L2 2MB -> 1MB/block. attn 63 -> 50us.
// R10 lesson: V 1MB -> 512KB/block was NEUTRAL: P3 L2 is off the critical
//      path. VALU-issue is constant ~24us across R7/R9/R10 => attn is now
//      issue-bound on SCALAR fp32 math (compiler does NOT SLP-pack float2).
// R11 lesson: VOP3P pk_f32 requires ALL operands to be VGPR PAIRS; a single
//      VGPR scalar src does not assemble. Broadcast a scalar by passing its
//      containing pair with op_sel:[s,..] op_sel_hi:[s,..] (same word both
//      lanes).
// R12: v_pk_fma_f32/v_pk_mul_f32 inline asm with pair+op_sel broadcasts.
//      Bit-identical math to R10; pure encoding A/B for packed-f32 rate.

#define B_ 4
#define Q_ 512
#define K_ 512
#define H_ 256
#define QE_ELEMS (B_ * Q_ * H_)           // 524288
#define KE_ELEMS (B_ * H_ * K_)           // 524288

static constexpr float CEXP = 2.8853900817779268f; // 2*log2(e)
static constexpr float LOG2E = 1.4426950408889634f;

typedef float v2f __attribute__((ext_vector_type(2)));
typedef float v4f __attribute__((ext_vector_type(4)));

// d = a*b + c (both lanes, one VOP3P issue)
__device__ __forceinline__ v2f pk_fma(v2f a, v2f b, v2f c) {
    v2f d;
    asm("v_pk_fma_f32 %0, %1, %2, %3" : "=v"(d) : "v"(a), "v"(b), "v"(c));
    return d;
}
// d = {a.x,a.x}*b + c  (broadcast LO word of pair a)
__device__ __forceinline__ v2f pk_fma_l(v2f a, v2f b, v2f c) {
    v2f d;
    asm("v_pk_fma_f32 %0, %1, %2, %3 op_sel:[0,0,0] op_sel_hi:[0,1,1]"
        : "=v"(d) : "v"(a), "v"(b), "v"(c));
    return d;
}
// d = {a.y,a.y}*b + c  (broadcast HI word of pair a)
__device__ __forceinline__ v2f pk_fma_h(v2f a, v2f b, v2f c) {
    v2f d;
    asm("v_pk_fma_f32 %0, %1, %2, %3 op_sel:[1,0,0] op_sel_hi:[1,1,1]"
        : "=v"(d) : "v"(a), "v"(b), "v"(c));
    return d;
}
__device__ __forceinline__ v2f pk_mul(v2f a, v2f b) {
    v2f d;
    asm("v_pk_mul_f32 %0, %1, %2" : "=v"(d) : "v"(a), "v"(b));
    return d;
}
// d = {a.y,a.y}*b  (broadcast HI word of pair a)
__device__ __forceinline__ v2f pk_mul_h(v2f a, v2f b) {
    v2f d;
    asm("v_pk_mul_f32 %0, %1, %2 op_sel:[1,0] op_sel_hi:[1,1]"
        : "=v"(d) : "v"(a), "v"(b));
    return d;
}

// ---------------------------------------------------------------------------
// proj_exp: 256 blocks x 1024 thr. Block = one 64x64 output tile; 4 teams of
// 256 thr each reduce a 64-d quarter (double-buffered LDS, reg prefetch);
// LDS combine -> exp2 -> store.  blocks [0,128): qe; [128,256): ke[b][h][k].
// ---------------------------------------------------------------------------
#define PJ_AS(team, buf, dd, row) smem[(((team)*2 + (buf)) * 16 + (dd)) * 68 + (row)]
#define PJ_SS(team, buf, dd, row) smem[8704 + (((team)*2 + (buf)) * 16 + (dd)) * 68 + (row)]

__global__ __launch_bounds__(1024, 4) void proj_exp(
    const float* __restrict__ queries, const float* __restrict__ keys,
    const float* __restrict__ Wq, const float* __restrict__ Wk,
    float* __restrict__ qe, float* __restrict__ ke)
{
    __shared__ __align__(16) float smem[17408];   // 69632 B

    const int bid = blockIdx.x;
    const int team = threadIdx.x >> 8;   // d-quarter 0..3 (64 d each)
    const int tid = threadIdx.x & 255;

    const float* A; const float* S; float* C; int ldc;
    if (bid < 128) {                 // qe: [B*Q=2048 x H=256], 32x4 tiles
        int mt = bid >> 2, nt = bid & 3;
        A = queries + (mt * 64) * H_;
        S = Wq + (nt * 64) * H_;
        C = qe + (mt * 64) * H_ + nt * 64;
        ldc = H_;
    } else {                         // ke: per-b [H=256 x K=512], 4x8 tiles
        int id = bid - 128;
        int b = id >> 5, mt = (id >> 3) & 3, nt = id & 7;
        A = Wk + (mt * 64) * H_;
        S = keys + ((long)(b * K_ + nt * 64)) * H_;
        C = ke + ((long)(b * H_ + mt * 64)) * K_ + nt * 64;
        ldc = K_;
    }

    const int tx = tid & 15;         // n0 = tx*4
    const int ty = tid >> 4;         // m0 = ty*4
    const int ldr = tid >> 2;        // staging row 0..63
    const int ldd = (tid & 3) * 4;   // staging d-offset 0,4,8,12
    const float* GA = A + ldr * H_ + team * 64 + ldd;
    const float* GS = S + ldr * H_ + team * 64 + ldd;

    float4 av = *(const float4*)GA;
    float4 sv = *(const float4*)GS;
    PJ_AS(team, 0, ldd + 0, ldr) = av.x; PJ_AS(team, 0, ldd + 1, ldr) = av.y;
    PJ_AS(team, 0, ldd + 2, ldr) = av.z; PJ_AS(team, 0, ldd + 3, ldr) = av.w;
    PJ_SS(team, 0, ldd + 0, ldr) = sv.x; PJ_SS(team, 0, ldd + 1, ldr) = sv.y;
    PJ_SS(team, 0, ldd + 2, ldr) = sv.z; PJ_SS(team, 0, ldd + 3, ldr) = sv.w;

    float acc[4][4] = {};
#pragma unroll
    for (int c = 0; c < 4; ++c) {    // 4 chunks x 16 d = 64 d per team
        const int cur = c & 1;
        if (c < 3) {                 // register prefetch of next chunk
            av = *(const float4*)(GA + (c + 1) * 16);
            sv = *(const float4*)(GS + (c + 1) * 16);
        }
        __syncthreads();             // buf[cur] writes visible
#pragma unroll
        for (int dd = 0; dd < 16; ++dd) {
            float4 a4 = *(const float4*)&PJ_AS(team, cur, dd, ty * 4);
            float4 b4 = *(const float4*)&PJ_SS(team, cur, dd, tx * 4);
            float am[4] = {a4.x, a4.y, a4.z, a4.w};
            float bn[4] = {b4.x, b4.y, b4.z, b4.w};
#pragma unroll
            for (int i = 0; i < 4; ++i)
#pragma unroll
                for (int j = 0; j < 4; ++j)
                    acc[i][j] = fmaf(am[i], bn[j], acc[i][j]);
        }
        if (c < 3) {                 // fill other buffer (last read 2 iters ago)
            const int nxt = cur ^ 1;
            PJ_AS(team, nxt, ldd + 0, ldr) = av.x;
            PJ_AS(team, nxt, ldd + 1, ldr) = av.y;
            PJ_AS(team, nxt, ldd + 2, ldr) = av.z;
            PJ_AS(team, nxt, ldd + 3, ldr) = av.w;
            PJ_SS(team, nxt, ldd + 0, ldr) = sv.x;
            PJ_SS(team, nxt, ldd + 1, ldr) = sv.y;
            PJ_SS(team, nxt, ldd + 2, ldr) = sv.z;
            PJ_SS(team, nxt, ldd + 3, ldr) = sv.w;
        }
    }

    // combine 4 d-quarter partials via LDS (reuse staging), exp, store
    __syncthreads();                 // all staging reads complete
    if (team > 0) {
        float* Cmb = smem + (team - 1) * 4352;   // 64 x 68 tile
#pragma unroll
        for (int i = 0; i < 4; ++i) {
            float4 o = {acc[i][0], acc[i][1], acc[i][2], acc[i][3]};
            *(float4*)&Cmb[(ty * 4 + i) * 68 + tx * 4] = o;
        }
    }
    __syncthreads();
    if (team == 0) {
#pragma unroll
        for (int i = 0; i < 4; ++i) {
            const int off = (ty * 4 + i) * 68 + tx * 4;
            float4 p1 = *(const float4*)&smem[off];
            float4 p2 = *(const float4*)&smem[4352 + off];
            float4 p3 = *(const float4*)&smem[8704 + off];
            float4 o;
            o.x = __builtin_amdgcn_exp2f(CEXP * (acc[i][0] + p1.x + p2.x + p3.x));
            o.y = __builtin_amdgcn_exp2f(CEXP * (acc[i][1] + p1.y + p2.y + p3.y));
            o.z = __builtin_amdgcn_exp2f(CEXP * (acc[i][2] + p1.z + p2.z + p3.z));
            o.w = __builtin_amdgcn_exp2f(CEXP * (acc[i][3] + p1.w + p2.w + p3.w));
            *(float4*)&C[(ty * 4 + i) * ldc + tx * 4] = o;
        }
    }
}

// ---------------------------------------------------------------------------
// attn: 512 blocks x 1024 thr (16 waves; 32-reg budget => 2 blocks/CU).
// XCD-affine: bid%8 -> XCD; XCD pair {2b,2b+1} serves batch b, so the hot set
// ke[b]+values[b] (~1MB) stays in that XCD's 4MB L2 (R5: FETCH 17->5MB).
// Phase 1: thread = (k-pair (t&255)*2, h-quarter t>>8); 4 q rows; quad-rcp;
//          v2f ke loads; runtime loop, unroll 2, depth-1 prefetch;
//          inner math forced to v_pk_fma_f32/v_pk_mul_f32 (R12).
// Phase 2: softmax, wave w<4 -> q row w.
// Phase 3: thread = (h-pair (t&127)*2, kq t>>7 of 8); ALL 4 q rows x 64 k x
//          2 h share ONE v2f V stream; pk_fma_l/_h (pair op_sel broadcast).
//          8 kq-partials -> sRed[8][4][256] = 32KB LDS reduce.
// ---------------------------------------------------------------------------
__global__ __launch_bounds__(1024, 8) void attn(
    const float* __restrict__ qe, const float* __restrict__ ke,
    const float* __restrict__ values, const float* __restrict__ wv,
    float* __restrict__ out)
{
    const int bid = blockIdx.x;
    const int xcd = bid & 7;
    const int b = xcd >> 1;
    const int q0 = (((bid >> 3) << 1) | (xcd & 1)) * 4;
    const int t = threadIdx.x;

    // flat LDS: sQ[4*256] | wvs[256] | sS[4*512] | sP[3][4*512]  (37.9 KB)
    // P3 reduce view: sRed[8][4][256] = 32KB (aliases sQ/wvs/sS)
    __shared__ __align__(16) float smem[9472];
    float* sQ  = smem;                   // [4][H_]
    float* wvs = smem + 4 * H_;          // [H_]
    float* sS  = smem + 5 * H_;          // [4][K_]
    float* sP  = smem + 5 * H_ + 4 * K_; // [3][4][K_]

    sQ[t] = qe[((long)(b * Q_ + q0 + (t >> 8))) * H_ + (t & 255)];
    if (t < H_) wvs[t] = wv[t];
    __syncthreads();

    // ---- Phase 1: scores
    {
        const int k2 = (t & 255) * 2;    // owns k2, k2+1 (contiguous)
        const int g = t >> 8;            // h-quarter: h in [g*64, g*64+64)
        const float* keb = ke + ((long)(b * H_ + g * 64)) * K_ + k2;

        v2f nx0 = *(const v2f*)(keb);
        v2f nx1 = *(const v2f*)(keb + K_);
        v2f nx2 = *(const v2f*)(keb + 2 * K_);
        v2f nx3 = *(const v2f*)(keb + 3 * K_);
        v2f acc[4] = {{0.f,0.f},{0.f,0.f},{0.f,0.f},{0.f,0.f}};
        const v2f one2 = {1.0f, 1.0f};

#pragma unroll 2
        for (int hl = 0; hl < 64; hl += 4) {
            v2f c0 = nx0, c1 = nx1, c2 = nx2, c3 = nx3;
            if (hl < 60) {               // depth-1 prefetch (runtime guard)
                const float* p = keb + (hl + 4) * K_;
                nx0 = *(const v2f*)(p);
                nx1 = *(const v2f*)(p + K_);
                nx2 = *(const v2f*)(p + 2 * K_);
                nx3 = *(const v2f*)(p + 3 * K_);
            }
            const int h = g * 64 + hl;
            v4f w4 = *(const v4f*)&wvs[h];
            const v2f wlo = w4.lo, whi = w4.hi;
#pragma unroll
            for (int q = 0; q < 4; ++q) {
                v4f e = *(const v4f*)&sQ[q * H_ + h];
                const v2f elo = e.lo, ehi = e.hi;
                v2f t0 = pk_fma_l(elo, c0, one2);   // 1 + e.x*c0
                v2f t1 = pk_fma_h(elo, c1, one2);   // 1 + e.y*c1
                v2f t2 = pk_fma_l(ehi, c2, one2);   // 1 + e.z*c2
                v2f t3 = pk_fma_h(ehi, c3, one2);   // 1 + e.w*c3
                v2f d01 = pk_mul(t0, t1);
                v2f d23 = pk_mul(t2, t3);
                v2f n01 = pk_fma_l(wlo, t1, pk_mul_h(wlo, t0)); // w.x*t1 + w.y*t0
                v2f n23 = pk_fma_l(whi, t3, pk_mul_h(whi, t2)); // w.z*t3 + w.w*t2
                v2f num = pk_fma(n01, d23, pk_mul(n23, d01));
                v2f den = pk_mul(d01, d23);
                v2f r;
                r.x = __builtin_amdgcn_rcpf(den.x);
                r.y = __builtin_amdgcn_rcpf(den.y);
                acc[q] = pk_fma(num, r, acc[q]);
            }
        }

        if (g > 0) {
            float* dst = sP + (g - 1) * 4 * K_;
#pragma unroll
            for (int q = 0; q < 4; ++q)
                *(v2f*)&dst[q * K_ + k2] = acc[q];
        }
        __syncthreads();
        if (g == 0) {
            const v2f m2 = {-2.0f, -2.0f};
#pragma unroll
            for (int q = 0; q < 4; ++q) {
                v2f p0 = *(const v2f*)&sP[0 * 4 * K_ + q * K_ + k2];
                v2f p1 = *(const v2f*)&sP[1 * 4 * K_ + q * K_ + k2];
                v2f p2 = *(const v2f*)&sP[2 * 4 * K_ + q * K_ + k2];
                v2f s = acc[q] + p0 + p1 + p2;
                *(v2f*)&sS[q * K_ + k2] = s * m2;
            }
        }
    }
    __syncthreads();

    // ---- Phase 2: softmax, wave w (w<4) -> q row w
    if (t < 256) {
        const int lane = t & 63;
        const int q = t >> 6;
        float sv[8];
        float m = -INFINITY;
#pragma unroll
        for (int j = 0; j < 8; ++j) {
            sv[j] = sS[q * K_ + lane + 64 * j];
            m = fmaxf(m, sv[j]);
        }
#pragma unroll
        for (int off = 32; off >= 1; off >>= 1) m = fmaxf(m, __shfl_xor(m, off));
        float sum = 0.f;
#pragma unroll
        for (int j = 0; j < 8; ++j) {
            sv[j] = __builtin_amdgcn_exp2f((sv[j] - m) * LOG2E);
            sum += sv[j];
        }
#pragma unroll
        for (int off = 32; off >= 1; off >>= 1) sum += __shfl_xor(sum, off);
        float rs = 1.0f / sum;
#pragma unroll
        for (int j = 0; j < 8; ++j) sS[q * K_ + lane + 64 * j] = sv[j] * rs;
    }
    __syncthreads();

    // ---- Phase 3: attn @ V. thread = (h-pair, k-eighth); all 4 q per thread
    {
        const int hp = t & 127;          // h-pair: h = 2*hp, 2*hp+1
        const int kq = t >> 7;           // k-eighth: 64 k
        const int kbeg = kq * 64;
        const float* vb = values + (long)b * K_ * H_ + hp * 2;

        v2f acc0 = {0.f, 0.f}, acc1 = {0.f, 0.f};
        v2f acc2 = {0.f, 0.f}, acc3 = {0.f, 0.f};
#pragma unroll 2
        for (int k = kbeg; k < kbeg + 64; k += 2) {
            v2f v0 = *(const v2f*)&vb[(k + 0) * H_];
            v2f v1 = *(const v2f*)&vb[(k + 1) * H_];
            v2f a0 = *(const v2f*)&sS[0 * K_ + k];  // wave-uniform bcast
            v2f a1 = *(const v2f*)&sS[1 * K_ + k];
            v2f a2 = *(const v2f*)&sS[2 * K_ + k];
            v2f a3 = *(const v2f*)&sS[3 * K_ + k];
            acc0 = pk_fma_l(a0, v0, pk_fma_h(a0, v1, acc0));
            acc1 = pk_fma_l(a1, v0, pk_fma_h(a1, v1, acc1));
            acc2 = pk_fma_l(a2, v0, pk_fma_h(a2, v1, acc2));
            acc3 = pk_fma_l(a3, v0, pk_fma_h(a3, v1, acc3));
        }

        __syncthreads();   // all sS reads done; smem becomes sRed[8][4][256]
        float* sRed = smem;
        *(v2f*)&sRed[(kq * 4 + 0) * 256 + hp * 2] = acc0;
        *(v2f*)&sRed[(kq * 4 + 1) * 256 + hp * 2] = acc1;
        *(v2f*)&sRed[(kq * 4 + 2) * 256 + hp * 2] = acc2;
        *(v2f*)&sRed[(kq * 4 + 3) * 256 + hp * 2] = acc3;
        __syncthreads();

        // final reduce: thread t -> output (q = t>>8, h = t&255)
        const int q = t >> 8;
        const int h = t & 255;
        float s = 0.f;
#pragma unroll
        for (int kk = 0; kk < 8; ++kk)
            s += sRed[(kk * 4 + q) * 256 + h];
        out[((long)(b * Q_ + q0 + q)) * H_ + h] = s;
    }
}

extern "C" void kernel_launch(void* const* d_in, const int* in_sizes, int n_in,
                              void* d_out, int out_size, void* d_ws, size_t ws_size,
                              hipStream_t stream) {
    const float* queries = (const float*)d_in[0];  // [B,Q,H]
    const float* keys    = (const float*)d_in[1];  // [B,K,H]
    const float* values  = (const float*)d_in[2];  // [B,K,H]
    const float* Wq      = (const float*)d_in[3];  // [H,H]
    const float* Wk      = (const float*)d_in[4];  // [H,H]
    const float* wv      = (const float*)d_in[5];  // [H]
    float* out = (float*)d_out;

    // ws: [qe 2MB][ke 2MB]
    float* qe = (float*)d_ws;
    float* ke = qe + QE_ELEMS;

    proj_exp<<<256, 1024, 0, stream>>>(queries, keys, Wq, Wk, qe, ke);
    attn<<<512, 1024, 0, stream>>>(qe, ke, values, wv, out);
}

// Round 6
// 117.425 us; speedup vs baseline: 1.0098x; 1.0098x over previous
//
#include <hip/hip_runtime.h>
#include <hip/hip_bf16.h>
#include <math.h>

// AdditiveAttention: B=4, Q=512, K=512, H=256, fp32.
// scores[b,q,k] = sum_h wv_h * tanh(qp + kp) -> softmax_k -> @V
// tanh(x) = 1 - 2/(1+e^{2x}); sum_h wv_h drops out of softmax.
// e^{2(q+k)} = e^{2q} * e^{2k}: exponentiate projections once (proj kernel).
// 4 h-terms share one rcp: sum wv_i/t_i = num/(t0*t1*t2*t3).
//
// R4 lesson: grid-barrier fusion => cross-XCD coherence storm. Two launches.
// R6 lesson: full unroll + reg prefetch + VGPR<=64 cap => scratch spill storm
//            (FETCH 410MB). Keep runtime loop + shallow prefetch.
// R8 lesson: 4q-acc + deep prefetch in P3 (48+ live regs vs the 32-reg budget
//            this compiler pins under launch_bounds(1024,8)) => spill storm
//            (WRITE 381MB, 160us). P3 live state MUST stay <= ~26-28 regs.
// R9: P3 q-pair sharing one V stream: V L2 2MB -> 1MB/block. attn 63 -> 50us.
// R10 lesson: V 1MB -> 512KB/block was NEUTRAL: P3 L2 BW off critical path.
// R11 lesson: VOP3P pk_f32 needs ALL operands as VGPR PAIRS; broadcast via
//            op_sel:[s,..] op_sel_hi:[s,..] on the containing pair.
// R12 lesson: packed f32 is ~issue-rate-NEUTRAL on gfx950 (157.3 TF spec ==
//            scalar rate; pk_fma ~2x scalar issue cycles). attn 49->47 only.
//            VALU-issue floor ~22us; remaining ~25us is STALL.
// R13: P3 depth-1 V prefetch (the only phase with zero prefetch; 2 dependent
//      8B loads vs 8 pk of work per iter = latency-bound). First pair issued
//      before the softmax barrier. Live regs ~28 (audited vs R8 lesson).

#define B_ 4
#define Q_ 512
#define K_ 512
#define H_ 256
#define QE_ELEMS (B_ * Q_ * H_)           // 524288
#define KE_ELEMS (B_ * H_ * K_)           // 524288

static constexpr float CEXP = 2.8853900817779268f; // 2*log2(e)
static constexpr float LOG2E = 1.4426950408889634f;

typedef float v2f __attribute__((ext_vector_type(2)));
typedef float v4f __attribute__((ext_vector_type(4)));

// d = a*b + c (both lanes, one VOP3P issue)
__device__ __forceinline__ v2f pk_fma(v2f a, v2f b, v2f c) {
    v2f d;
    asm("v_pk_fma_f32 %0, %1, %2, %3" : "=v"(d) : "v"(a), "v"(b), "v"(c));
    return d;
}
// d = {a.x,a.x}*b + c  (broadcast LO word of pair a)
__device__ __forceinline__ v2f pk_fma_l(v2f a, v2f b, v2f c) {
    v2f d;
    asm("v_pk_fma_f32 %0, %1, %2, %3 op_sel:[0,0,0] op_sel_hi:[0,1,1]"
        : "=v"(d) : "v"(a), "v"(b), "v"(c));
    return d;
}
// d = {a.y,a.y}*b + c  (broadcast HI word of pair a)
__device__ __forceinline__ v2f pk_fma_h(v2f a, v2f b, v2f c) {
    v2f d;
    asm("v_pk_fma_f32 %0, %1, %2, %3 op_sel:[1,0,0] op_sel_hi:[1,1,1]"
        : "=v"(d) : "v"(a), "v"(b), "v"(c));
    return d;
}
__device__ __forceinline__ v2f pk_mul(v2f a, v2f b) {
    v2f d;
    asm("v_pk_mul_f32 %0, %1, %2" : "=v"(d) : "v"(a), "v"(b));
    return d;
}
// d = {a.y,a.y}*b  (broadcast HI word of pair a)
__device__ __forceinline__ v2f pk_mul_h(v2f a, v2f b) {
    v2f d;
    asm("v_pk_mul_f32 %0, %1, %2 op_sel:[1,0] op_sel_hi:[1,1]"
        : "=v"(d) : "v"(a), "v"(b));
    return d;
}

// ---------------------------------------------------------------------------
// proj_exp: 256 blocks x 1024 thr. Block = one 64x64 output tile; 4 teams of
// 256 thr each reduce a 64-d quarter (double-buffered LDS, reg prefetch);
// LDS combine -> exp2 -> store.  blocks [0,128): qe; [128,256): ke[b][h][k].
// ---------------------------------------------------------------------------
#define PJ_AS(team, buf, dd, row) smem[(((team)*2 + (buf)) * 16 + (dd)) * 68 + (row)]
#define PJ_SS(team, buf, dd, row) smem[8704 + (((team)*2 + (buf)) * 16 + (dd)) * 68 + (row)]

__global__ __launch_bounds__(1024, 4) void proj_exp(
    const float* __restrict__ queries, const float* __restrict__ keys,
    const float* __restrict__ Wq, const float* __restrict__ Wk,
    float* __restrict__ qe, float* __restrict__ ke)
{
    __shared__ __align__(16) float smem[17408];   // 69632 B

    const int bid = blockIdx.x;
    const int team = threadIdx.x >> 8;   // d-quarter 0..3 (64 d each)
    const int tid = threadIdx.x & 255;

    const float* A; const float* S; float* C; int ldc;
    if (bid < 128) {                 // qe: [B*Q=2048 x H=256], 32x4 tiles
        int mt = bid >> 2, nt = bid & 3;
        A = queries + (mt * 64) * H_;
        S = Wq + (nt * 64) * H_;
        C = qe + (mt * 64) * H_ + nt * 64;
        ldc = H_;
    } else {                         // ke: per-b [H=256 x K=512], 4x8 tiles
        int id = bid - 128;
        int b = id >> 5, mt = (id >> 3) & 3, nt = id & 7;
        A = Wk + (mt * 64) * H_;
        S = keys + ((long)(b * K_ + nt * 64)) * H_;
        C = ke + ((long)(b * H_ + mt * 64)) * K_ + nt * 64;
        ldc = K_;
    }

    const int tx = tid & 15;         // n0 = tx*4
    const int ty = tid >> 4;         // m0 = ty*4
    const int ldr = tid >> 2;        // staging row 0..63
    const int ldd = (tid & 3) * 4;   // staging d-offset 0,4,8,12
    const float* GA = A + ldr * H_ + team * 64 + ldd;
    const float* GS = S + ldr * H_ + team * 64 + ldd;

    float4 av = *(const float4*)GA;
    float4 sv = *(const float4*)GS;
    PJ_AS(team, 0, ldd + 0, ldr) = av.x; PJ_AS(team, 0, ldd + 1, ldr) = av.y;
    PJ_AS(team, 0, ldd + 2, ldr) = av.z; PJ_AS(team, 0, ldd + 3, ldr) = av.w;
    PJ_SS(team, 0, ldd + 0, ldr) = sv.x; PJ_SS(team, 0, ldd + 1, ldr) = sv.y;
    PJ_SS(team, 0, ldd + 2, ldr) = sv.z; PJ_SS(team, 0, ldd + 3, ldr) = sv.w;

    float acc[4][4] = {};
#pragma unroll
    for (int c = 0; c < 4; ++c) {    // 4 chunks x 16 d = 64 d per team
        const int cur = c & 1;
        if (c < 3) {                 // register prefetch of next chunk
            av = *(const float4*)(GA + (c + 1) * 16);
            sv = *(const float4*)(GS + (c + 1) * 16);
        }
        __syncthreads();             // buf[cur] writes visible
#pragma unroll
        for (int dd = 0; dd < 16; ++dd) {
            float4 a4 = *(const float4*)&PJ_AS(team, cur, dd, ty * 4);
            float4 b4 = *(const float4*)&PJ_SS(team, cur, dd, tx * 4);
            float am[4] = {a4.x, a4.y, a4.z, a4.w};
            float bn[4] = {b4.x, b4.y, b4.z, b4.w};
#pragma unroll
            for (int i = 0; i < 4; ++i)
#pragma unroll
                for (int j = 0; j < 4; ++j)
                    acc[i][j] = fmaf(am[i], bn[j], acc[i][j]);
        }
        if (c < 3) {                 // fill other buffer (last read 2 iters ago)
            const int nxt = cur ^ 1;
            PJ_AS(team, nxt, ldd + 0, ldr) = av.x;
            PJ_AS(team, nxt, ldd + 1, ldr) = av.y;
            PJ_AS(team, nxt, ldd + 2, ldr) = av.z;
            PJ_AS(team, nxt, ldd + 3, ldr) = av.w;
            PJ_SS(team, nxt, ldd + 0, ldr) = sv.x;
            PJ_SS(team, nxt, ldd + 1, ldr) = sv.y;
            PJ_SS(team, nxt, ldd + 2, ldr) = sv.z;
            PJ_SS(team, nxt, ldd + 3, ldr) = sv.w;
        }
    }

    // combine 4 d-quarter partials via LDS (reuse staging), exp, store
    __syncthreads();                 // all staging reads complete
    if (team > 0) {
        float* Cmb = smem + (team - 1) * 4352;   // 64 x 68 tile
#pragma unroll
        for (int i = 0; i < 4; ++i) {
            float4 o = {acc[i][0], acc[i][1], acc[i][2], acc[i][3]};
            *(float4*)&Cmb[(ty * 4 + i) * 68 + tx * 4] = o;
        }
    }
    __syncthreads();
    if (team == 0) {
#pragma unroll
        for (int i = 0; i < 4; ++i) {
            const int off = (ty * 4 + i) * 68 + tx * 4;
            float4 p1 = *(const float4*)&smem[off];
            float4 p2 = *(const float4*)&smem[4352 + off];
            float4 p3 = *(const float4*)&smem[8704 + off];
            float4 o;
            o.x = __builtin_amdgcn_exp2f(CEXP * (acc[i][0] + p1.x + p2.x + p3.x));
            o.y = __builtin_amdgcn_exp2f(CEXP * (acc[i][1] + p1.y + p2.y + p3.y));
            o.z = __builtin_amdgcn_exp2f(CEXP * (acc[i][2] + p1.z + p2.z + p3.z));
            o.w = __builtin_amdgcn_exp2f(CEXP * (acc[i][3] + p1.w + p2.w + p3.w));
            *(float4*)&C[(ty * 4 + i) * ldc + tx * 4] = o;
        }
    }
}

// ---------------------------------------------------------------------------
// attn: 512 blocks x 1024 thr (16 waves; 32-reg budget => 2 blocks/CU).
// XCD-affine: bid%8 -> XCD; XCD pair {2b,2b+1} serves batch b, so the hot set
// ke[b]+values[b] (~1MB) stays in that XCD's 4MB L2 (R5: FETCH 17->5MB).
// Phase 1: thread = (k-pair (t&255)*2, h-quarter t>>8); 4 q rows; quad-rcp;
//          v2f ke loads; runtime loop, unroll 2, depth-1 prefetch;
//          inner math forced to v_pk_fma_f32/v_pk_mul_f32 (R12).
// Phase 2: softmax, wave w<4 -> q row w.
// Phase 3: thread = (h-pair (t&127)*2, kq t>>7 of 8); ALL 4 q rows x 64 k x
//          2 h share ONE v2f V stream; pk_fma_l/_h (pair op_sel broadcast);
//          depth-1 prefetch, first pair issued pre-barrier (R13).
//          8 kq-partials -> sRed[8][4][256] = 32KB LDS reduce.
// ---------------------------------------------------------------------------
__global__ __launch_bounds__(1024, 8) void attn(
    const float* __restrict__ qe, const float* __restrict__ ke,
    const float* __restrict__ values, const float* __restrict__ wv,
    float* __restrict__ out)
{
    const int bid = blockIdx.x;
    const int xcd = bid & 7;
    const int b = xcd >> 1;
    const int q0 = (((bid >> 3) << 1) | (xcd & 1)) * 4;
    const int t = threadIdx.x;

    // flat LDS: sQ[4*256] | wvs[256] | sS[4*512] | sP[3][4*512]  (37.9 KB)
    // P3 reduce view: sRed[8][4][256] = 32KB (aliases sQ/wvs/sS)
    __shared__ __align__(16) float smem[9472];
    float* sQ  = smem;                   // [4][H_]
    float* wvs = smem + 4 * H_;          // [H_]
    float* sS  = smem + 5 * H_;          // [4][K_]
    float* sP  = smem + 5 * H_ + 4 * K_; // [3][4][K_]

    sQ[t] = qe[((long)(b * Q_ + q0 + (t >> 8))) * H_ + (t & 255)];
    if (t < H_) wvs[t] = wv[t];
    __syncthreads();

    // ---- Phase 1: scores
    {
        const int k2 = (t & 255) * 2;    // owns k2, k2+1 (contiguous)
        const int g = t >> 8;            // h-quarter: h in [g*64, g*64+64)
        const float* keb = ke + ((long)(b * H_ + g * 64)) * K_ + k2;

        v2f nx0 = *(const v2f*)(keb);
        v2f nx1 = *(const v2f*)(keb + K_);
        v2f nx2 = *(const v2f*)(keb + 2 * K_);
        v2f nx3 = *(const v2f*)(keb + 3 * K_);
        v2f acc[4] = {{0.f,0.f},{0.f,0.f},{0.f,0.f},{0.f,0.f}};
        const v2f one2 = {1.0f, 1.0f};

#pragma unroll 2
        for (int hl = 0; hl < 64; hl += 4) {
            v2f c0 = nx0, c1 = nx1, c2 = nx2, c3 = nx3;
            if (hl < 60) {               // depth-1 prefetch (runtime guard)
                const float* p = keb + (hl + 4) * K_;
                nx0 = *(const v2f*)(p);
                nx1 = *(const v2f*)(p + K_);
                nx2 = *(const v2f*)(p + 2 * K_);
                nx3 = *(const v2f*)(p + 3 * K_);
            }
            const int h = g * 64 + hl;
            v4f w4 = *(const v4f*)&wvs[h];
            const v2f wlo = w4.lo, whi = w4.hi;
#pragma unroll
            for (int q = 0; q < 4; ++q) {
                v4f e = *(const v4f*)&sQ[q * H_ + h];
                const v2f elo = e.lo, ehi = e.hi;
                v2f t0 = pk_fma_l(elo, c0, one2);   // 1 + e.x*c0
                v2f t1 = pk_fma_h(elo, c1, one2);   // 1 + e.y*c1
                v2f t2 = pk_fma_l(ehi, c2, one2);   // 1 + e.z*c2
                v2f t3 = pk_fma_h(ehi, c3, one2);   // 1 + e.w*c3
                v2f d01 = pk_mul(t0, t1);
                v2f d23 = pk_mul(t2, t3);
                v2f n01 = pk_fma_l(wlo, t1, pk_mul_h(wlo, t0)); // w.x*t1 + w.y*t0
                v2f n23 = pk_fma_l(whi, t3, pk_mul_h(whi, t2)); // w.z*t3 + w.w*t2
                v2f num = pk_fma(n01, d23, pk_mul(n23, d01));
                v2f den = pk_mul(d01, d23);
                v2f r;
                r.x = __builtin_amdgcn_rcpf(den.x);
                r.y = __builtin_amdgcn_rcpf(den.y);
                acc[q] = pk_fma(num, r, acc[q]);
            }
        }

        if (g > 0) {
            float* dst = sP + (g - 1) * 4 * K_;
#pragma unroll
            for (int q = 0; q < 4; ++q)
                *(v2f*)&dst[q * K_ + k2] = acc[q];
        }
        __syncthreads();
        if (g == 0) {
            const v2f m2 = {-2.0f, -2.0f};
#pragma unroll
            for (int q = 0; q < 4; ++q) {
                v2f p0 = *(const v2f*)&sP[0 * 4 * K_ + q * K_ + k2];
                v2f p1 = *(const v2f*)&sP[1 * 4 * K_ + q * K_ + k2];
                v2f p2 = *(const v2f*)&sP[2 * 4 * K_ + q * K_ + k2];
                v2f s = acc[q] + p0 + p1 + p2;
                *(v2f*)&sS[q * K_ + k2] = s * m2;
            }
        }
    }
    __syncthreads();

    // ---- Phase 2: softmax, wave w (w<4) -> q row w
    if (t < 256) {
        const int lane = t & 63;
        const int q = t >> 6;
        float sv[8];
        float m = -INFINITY;
#pragma unroll
        for (int j = 0; j < 8; ++j) {
            sv[j] = sS[q * K_ + lane + 64 * j];
            m = fmaxf(m, sv[j]);
        }
#pragma unroll
        for (int off = 32; off >= 1; off >>= 1) m = fmaxf(m, __shfl_xor(m, off));
        float sum = 0.f;
#pragma unroll
        for (int j = 0; j < 8; ++j) {
            sv[j] = __builtin_amdgcn_exp2f((sv[j] - m) * LOG2E);
            sum += sv[j];
        }
#pragma unroll
        for (int off = 32; off >= 1; off >>= 1) sum += __shfl_xor(sum, off);
        float rs = 1.0f / sum;
#pragma unroll
        for (int j = 0; j < 8; ++j) sS[q * K_ + lane + 64 * j] = sv[j] * rs;
    }

    // ---- Phase 3 setup: issue first V pair BEFORE the softmax barrier
    const int hp = t & 127;          // h-pair: h = 2*hp, 2*hp+1
    const int kq = t >> 7;           // k-eighth: 64 k
    const int kbeg = kq * 64;
    const float* vb = values + (long)b * K_ * H_ + hp * 2;

    v2f pv0 = *(const v2f*)&vb[(kbeg + 0) * H_];
    v2f pv1 = *(const v2f*)&vb[(kbeg + 1) * H_];

    __syncthreads();                 // sS (softmaxed weights) ready

    // ---- Phase 3: attn @ V. thread = (h-pair, k-eighth); all 4 q per thread
    {
        v2f acc0 = {0.f, 0.f}, acc1 = {0.f, 0.f};
        v2f acc2 = {0.f, 0.f}, acc3 = {0.f, 0.f};
#pragma unroll 2
        for (int k = kbeg; k < kbeg + 64; k += 2) {
            v2f v0 = pv0, v1 = pv1;
            if (k + 2 < kbeg + 64) { // depth-1 prefetch (runtime guard)
                pv0 = *(const v2f*)&vb[(k + 2) * H_];
                pv1 = *(const v2f*)&vb[(k + 3) * H_];
            }
            v2f a0 = *(const v2f*)&sS[0 * K_ + k];  // wave-uniform bcast
            v2f a1 = *(const v2f*)&sS[1 * K_ + k];
            v2f a2 = *(const v2f*)&sS[2 * K_ + k];
            v2f a3 = *(const v2f*)&sS[3 * K_ + k];
            acc0 = pk_fma_l(a0, v0, pk_fma_h(a0, v1, acc0));
            acc1 = pk_fma_l(a1, v0, pk_fma_h(a1, v1, acc1));
            acc2 = pk_fma_l(a2, v0, pk_fma_h(a2, v1, acc2));
            acc3 = pk_fma_l(a3, v0, pk_fma_h(a3, v1, acc3));
        }

        __syncthreads();   // all sS reads done; smem becomes sRed[8][4][256]
        float* sRed = smem;
        *(v2f*)&sRed[(kq * 4 + 0) * 256 + hp * 2] = acc0;
        *(v2f*)&sRed[(kq * 4 + 1) * 256 + hp * 2] = acc1;
        *(v2f*)&sRed[(kq * 4 + 2) * 256 + hp * 2] = acc2;
        *(v2f*)&sRed[(kq * 4 + 3) * 256 + hp * 2] = acc3;
        __syncthreads();

        // final reduce: thread t -> output (q = t>>8, h = t&255)
        const int q = t >> 8;
        const int h = t & 255;
        float s = 0.f;
#pragma unroll
        for (int kk = 0; kk < 8; ++kk)
            s += sRed[(kk * 4 + q) * 256 + h];
        out[((long)(b * Q_ + q0 + q)) * H_ + h] = s;
    }
}

extern "C" void kernel_launch(void* const* d_in, const int* in_sizes, int n_in,
                              void* d_out, int out_size, void* d_ws, size_t ws_size,
                              hipStream_t stream) {
    const float* queries = (const float*)d_in[0];  // [B,Q,H]
    const float* keys    = (const float*)d_in[1];  // [B,K,H]
    const float* values  = (const float*)d_in[2];  // [B,K,H]
    const float* Wq      = (const float*)d_in[3];  // [H,H]
    const float* Wk      = (const float*)d_in[4];  // [H,H]
    const float* wv      = (const float*)d_in[5];  // [H]
    float* out = (float*)d_out;

    // ws: [qe 2MB][ke 2MB]
    float* qe = (float*)d_ws;
    float* ke = qe + QE_ELEMS;

    proj_exp<<<256, 1024, 0, stream>>>(queries, keys, Wq, Wk, qe, ke);
    attn<<<512, 1024, 0, stream>>>(qe, ke, values, wv, out);
}

// Round 7
// 113.056 us; speedup vs baseline: 1.0488x; 1.0386x over previous
//
#include <hip/hip_runtime.h>
#include <hip/hip_bf16.h>
#include <math.h>

// AdditiveAttention: B=4, Q=512, K=512, H=256, fp32.
// scores[b,q,k] = sum_h wv_h * tanh(qp + kp) -> softmax_k -> @V
// tanh(x) = 1 - 2/(1+e^{2x}); sum_h wv_h drops out of softmax.
// e^{2(q+k)} = e^{2q} * e^{2k}: exponentiate projections once (proj kernel).
// 4 h-terms share one rcp: sum wv_i/t_i = num/(t0*t1*t2*t3).
//
// R4 lesson: grid-barrier fusion => cross-XCD coherence storm. Two launches.
// R6 lesson: full unroll + reg prefetch over budget => scratch spill storm.
// R8 lesson: spill when LIVE set exceeds the VGPR budget. CORRECTION (R14):
//            launch_bounds(1024,8) budget is 64 VGPR (512/8), not 32 — R8's
//            acc16+prefetch16+copies16+misc ~62+ tipped it. Named-reg
//            double-buffering (no copies) at ~46 live is safe.
// R9: P3 q-pair one V stream: attn 63 -> 50us (P3 was per-CU L2-BW bound).
// R10 lesson: further V traffic cuts NEUTRAL: L2 BW off critical path.
// R11 lesson: VOP3P pk_f32 needs ALL operands as VGPR PAIRS; broadcast via
//            op_sel:[s,..] op_sel_hi:[s,..] on the containing pair.
// R12 lesson: packed f32 is ~issue-rate-NEUTRAL on gfx950 (157.3 TF spec ==
//            scalar rate). VALU-issue floor ~24us; rest is stall.
// R13: P3 depth-1 V prefetch: 47.1 -> 45.7us.
// R14: spend the reg headroom: P3 = (h-quad, kq/16) float4 V loads, 4 q accs,
//      named-reg prefetch (~46 live). Fuse partial-combine INTO softmax
//      (all 4 teams write sP; drop combine pass + 1 barrier + 8KB roundtrip).
//      sRed[16][4][256] = 64KB LDS (128KB/CU @ 2 blocks, fits 160KB).

#define B_ 4
#define Q_ 512
#define K_ 512
#define H_ 256
#define QE_ELEMS (B_ * Q_ * H_)           // 524288
#define KE_ELEMS (B_ * H_ * K_)           // 524288

static constexpr float CEXP = 2.8853900817779268f; // 2*log2(e)
static constexpr float LOG2E = 1.4426950408889634f;

typedef float v2f __attribute__((ext_vector_type(2)));
typedef float v4f __attribute__((ext_vector_type(4)));

// d = a*b + c (both lanes, one VOP3P issue)
__device__ __forceinline__ v2f pk_fma(v2f a, v2f b, v2f c) {
    v2f d;
    asm("v_pk_fma_f32 %0, %1, %2, %3" : "=v"(d) : "v"(a), "v"(b), "v"(c));
    return d;
}
// d = {a.x,a.x}*b + c  (broadcast LO word of pair a)
__device__ __forceinline__ v2f pk_fma_l(v2f a, v2f b, v2f c) {
    v2f d;
    asm("v_pk_fma_f32 %0, %1, %2, %3 op_sel:[0,0,0] op_sel_hi:[0,1,1]"
        : "=v"(d) : "v"(a), "v"(b), "v"(c));
    return d;
}
// d = {a.y,a.y}*b + c  (broadcast HI word of pair a)
__device__ __forceinline__ v2f pk_fma_h(v2f a, v2f b, v2f c) {
    v2f d;
    asm("v_pk_fma_f32 %0, %1, %2, %3 op_sel:[1,0,0] op_sel_hi:[1,1,1]"
        : "=v"(d) : "v"(a), "v"(b), "v"(c));
    return d;
}
__device__ __forceinline__ v2f pk_mul(v2f a, v2f b) {
    v2f d;
    asm("v_pk_mul_f32 %0, %1, %2" : "=v"(d) : "v"(a), "v"(b));
    return d;
}
// d = {a.y,a.y}*b  (broadcast HI word of pair a)
__device__ __forceinline__ v2f pk_mul_h(v2f a, v2f b) {
    v2f d;
    asm("v_pk_mul_f32 %0, %1, %2 op_sel:[1,0] op_sel_hi:[1,1]"
        : "=v"(d) : "v"(a), "v"(b));
    return d;
}
// float4 forms: broadcast scalar (lo/hi word of pair a) across both halves
__device__ __forceinline__ v4f pk4_fma_l(v2f a, v4f b, v4f c) {
    v4f d;
    d.lo = pk_fma_l(a, b.lo, c.lo);
    d.hi = pk_fma_l(a, b.hi, c.hi);
    return d;
}
__device__ __forceinline__ v4f pk4_fma_h(v2f a, v4f b, v4f c) {
    v4f d;
    d.lo = pk_fma_h(a, b.lo, c.lo);
    d.hi = pk_fma_h(a, b.hi, c.hi);
    return d;
}

// ---------------------------------------------------------------------------
// proj_exp: 256 blocks x 1024 thr. Block = one 64x64 output tile; 4 teams of
// 256 thr each reduce a 64-d quarter (double-buffered LDS, reg prefetch);
// LDS combine -> exp2 -> store.  blocks [0,128): qe; [128,256): ke[b][h][k].
// ---------------------------------------------------------------------------
#define PJ_AS(team, buf, dd, row) smem[(((team)*2 + (buf)) * 16 + (dd)) * 68 + (row)]
#define PJ_SS(team, buf, dd, row) smem[8704 + (((team)*2 + (buf)) * 16 + (dd)) * 68 + (row)]

__global__ __launch_bounds__(1024, 4) void proj_exp(
    const float* __restrict__ queries, const float* __restrict__ keys,
    const float* __restrict__ Wq, const float* __restrict__ Wk,
    float* __restrict__ qe, float* __restrict__ ke)
{
    __shared__ __align__(16) float smem[17408];   // 69632 B

    const int bid = blockIdx.x;
    const int team = threadIdx.x >> 8;   // d-quarter 0..3 (64 d each)
    const int tid = threadIdx.x & 255;

    const float* A; const float* S; float* C; int ldc;
    if (bid < 128) {                 // qe: [B*Q=2048 x H=256], 32x4 tiles
        int mt = bid >> 2, nt = bid & 3;
        A = queries + (mt * 64) * H_;
        S = Wq + (nt * 64) * H_;
        C = qe + (mt * 64) * H_ + nt * 64;
        ldc = H_;
    } else {                         // ke: per-b [H=256 x K=512], 4x8 tiles
        int id = bid - 128;
        int b = id >> 5, mt = (id >> 3) & 3, nt = id & 7;
        A = Wk + (mt * 64) * H_;
        S = keys + ((long)(b * K_ + nt * 64)) * H_;
        C = ke + ((long)(b * H_ + mt * 64)) * K_ + nt * 64;
        ldc = K_;
    }

    const int tx = tid & 15;         // n0 = tx*4
    const int ty = tid >> 4;         // m0 = ty*4
    const int ldr = tid >> 2;        // staging row 0..63
    const int ldd = (tid & 3) * 4;   // staging d-offset 0,4,8,12
    const float* GA = A + ldr * H_ + team * 64 + ldd;
    const float* GS = S + ldr * H_ + team * 64 + ldd;

    float4 av = *(const float4*)GA;
    float4 sv = *(const float4*)GS;
    PJ_AS(team, 0, ldd + 0, ldr) = av.x; PJ_AS(team, 0, ldd + 1, ldr) = av.y;
    PJ_AS(team, 0, ldd + 2, ldr) = av.z; PJ_AS(team, 0, ldd + 3, ldr) = av.w;
    PJ_SS(team, 0, ldd + 0, ldr) = sv.x; PJ_SS(team, 0, ldd + 1, ldr) = sv.y;
    PJ_SS(team, 0, ldd + 2, ldr) = sv.z; PJ_SS(team, 0, ldd + 3, ldr) = sv.w;

    float acc[4][4] = {};
#pragma unroll
    for (int c = 0; c < 4; ++c) {    // 4 chunks x 16 d = 64 d per team
        const int cur = c & 1;
        if (c < 3) {                 // register prefetch of next chunk
            av = *(const float4*)(GA + (c + 1) * 16);
            sv = *(const float4*)(GS + (c + 1) * 16);
        }
        __syncthreads();             // buf[cur] writes visible
#pragma unroll
        for (int dd = 0; dd < 16; ++dd) {
            float4 a4 = *(const float4*)&PJ_AS(team, cur, dd, ty * 4);
            float4 b4 = *(const float4*)&PJ_SS(team, cur, dd, tx * 4);
            float am[4] = {a4.x, a4.y, a4.z, a4.w};
            float bn[4] = {b4.x, b4.y, b4.z, b4.w};
#pragma unroll
            for (int i = 0; i < 4; ++i)
#pragma unroll
                for (int j = 0; j < 4; ++j)
                    acc[i][j] = fmaf(am[i], bn[j], acc[i][j]);
        }
        if (c < 3) {                 // fill other buffer (last read 2 iters ago)
            const int nxt = cur ^ 1;
            PJ_AS(team, nxt, ldd + 0, ldr) = av.x;
            PJ_AS(team, nxt, ldd + 1, ldr) = av.y;
            PJ_AS(team, nxt, ldd + 2, ldr) = av.z;
            PJ_AS(team, nxt, ldd + 3, ldr) = av.w;
            PJ_SS(team, nxt, ldd + 0, ldr) = sv.x;
            PJ_SS(team, nxt, ldd + 1, ldr) = sv.y;
            PJ_SS(team, nxt, ldd + 2, ldr) = sv.z;
            PJ_SS(team, nxt, ldd + 3, ldr) = sv.w;
        }
    }

    // combine 4 d-quarter partials via LDS (reuse staging), exp, store
    __syncthreads();                 // all staging reads complete
    if (team > 0) {
        float* Cmb = smem + (team - 1) * 4352;   // 64 x 68 tile
#pragma unroll
        for (int i = 0; i < 4; ++i) {
            float4 o = {acc[i][0], acc[i][1], acc[i][2], acc[i][3]};
            *(float4*)&Cmb[(ty * 4 + i) * 68 + tx * 4] = o;
        }
    }
    __syncthreads();
    if (team == 0) {
#pragma unroll
        for (int i = 0; i < 4; ++i) {
            const int off = (ty * 4 + i) * 68 + tx * 4;
            float4 p1 = *(const float4*)&smem[off];
            float4 p2 = *(const float4*)&smem[4352 + off];
            float4 p3 = *(const float4*)&smem[8704 + off];
            float4 o;
            o.x = __builtin_amdgcn_exp2f(CEXP * (acc[i][0] + p1.x + p2.x + p3.x));
            o.y = __builtin_amdgcn_exp2f(CEXP * (acc[i][1] + p1.y + p2.y + p3.y));
            o.z = __builtin_amdgcn_exp2f(CEXP * (acc[i][2] + p1.z + p2.z + p3.z));
            o.w = __builtin_amdgcn_exp2f(CEXP * (acc[i][3] + p1.w + p2.w + p3.w));
            *(float4*)&C[(ty * 4 + i) * ldc + tx * 4] = o;
        }
    }
}

// ---------------------------------------------------------------------------
// attn: 512 blocks x 1024 thr (16 waves; 64-VGPR budget => 2 blocks/CU).
// XCD-affine: bid%8 -> XCD; XCD pair {2b,2b+1} serves batch b, so the hot set
// ke[b]+values[b] (~1MB) stays in that XCD's 4MB L2 (R5: FETCH 17->5MB).
// Phase 1: thread = (k-pair (t&255)*2, h-quarter t>>8); 4 q rows; quad-rcp;
//          v2f ke loads; depth-1 prefetch; pk math (R12). ALL teams write sP.
// Phase 2 (R14): fused combine+softmax: wave w<4 -> q row w, reads 4 sP
//          partials directly (no separate combine pass/barrier).
// Phase 3 (R14): thread = (h-quad (t&63)*4, kq t>>6 of 16); ALL 4 q rows x
//          32 k x 4 h; float4 V loads, named-reg depth-1 prefetch (~46 live);
//          16 kq-partials -> sRed[16][4][256] = 64KB LDS reduce.
// ---------------------------------------------------------------------------
__global__ __launch_bounds__(1024, 8) void attn(
    const float* __restrict__ qe, const float* __restrict__ ke,
    const float* __restrict__ values, const float* __restrict__ wv,
    float* __restrict__ out)
{
    const int bid = blockIdx.x;
    const int xcd = bid & 7;
    const int b = xcd >> 1;
    const int q0 = (((bid >> 3) << 1) | (xcd & 1)) * 4;
    const int t = threadIdx.x;

    // flat LDS 64KB. P1/P2 view: sQ[4*256] | wvs[256] | sS[4*512] | sP[4][4*512]
    //                P3 reduce view: sRed[16][4][256] (aliases everything)
    __shared__ __align__(16) float smem[16384];
    float* sQ  = smem;                   // [4][H_]
    float* wvs = smem + 4 * H_;          // [H_]
    float* sS  = smem + 5 * H_;          // [4][K_]
    float* sP  = smem + 5 * H_ + 4 * K_; // [4][4][K_]

    sQ[t] = qe[((long)(b * Q_ + q0 + (t >> 8))) * H_ + (t & 255)];
    if (t < H_) wvs[t] = wv[t];
    __syncthreads();

    // ---- Phase 1: scores
    {
        const int k2 = (t & 255) * 2;    // owns k2, k2+1 (contiguous)
        const int g = t >> 8;            // h-quarter: h in [g*64, g*64+64)
        const float* keb = ke + ((long)(b * H_ + g * 64)) * K_ + k2;

        v2f nx0 = *(const v2f*)(keb);
        v2f nx1 = *(const v2f*)(keb + K_);
        v2f nx2 = *(const v2f*)(keb + 2 * K_);
        v2f nx3 = *(const v2f*)(keb + 3 * K_);
        v2f acc[4] = {{0.f,0.f},{0.f,0.f},{0.f,0.f},{0.f,0.f}};
        const v2f one2 = {1.0f, 1.0f};

#pragma unroll 2
        for (int hl = 0; hl < 64; hl += 4) {
            v2f c0 = nx0, c1 = nx1, c2 = nx2, c3 = nx3;
            if (hl < 60) {               // depth-1 prefetch (runtime guard)
                const float* p = keb + (hl + 4) * K_;
                nx0 = *(const v2f*)(p);
                nx1 = *(const v2f*)(p + K_);
                nx2 = *(const v2f*)(p + 2 * K_);
                nx3 = *(const v2f*)(p + 3 * K_);
            }
            const int h = g * 64 + hl;
            v4f w4 = *(const v4f*)&wvs[h];
            const v2f wlo = w4.lo, whi = w4.hi;
#pragma unroll
            for (int q = 0; q < 4; ++q) {
                v4f e = *(const v4f*)&sQ[q * H_ + h];
                const v2f elo = e.lo, ehi = e.hi;
                v2f t0 = pk_fma_l(elo, c0, one2);   // 1 + e.x*c0
                v2f t1 = pk_fma_h(elo, c1, one2);   // 1 + e.y*c1
                v2f t2 = pk_fma_l(ehi, c2, one2);   // 1 + e.z*c2
                v2f t3 = pk_fma_h(ehi, c3, one2);   // 1 + e.w*c3
                v2f d01 = pk_mul(t0, t1);
                v2f d23 = pk_mul(t2, t3);
                v2f n01 = pk_fma_l(wlo, t1, pk_mul_h(wlo, t0)); // w.x*t1 + w.y*t0
                v2f n23 = pk_fma_l(whi, t3, pk_mul_h(whi, t2)); // w.z*t3 + w.w*t2
                v2f num = pk_fma(n01, d23, pk_mul(n23, d01));
                v2f den = pk_mul(d01, d23);
                v2f r;
                r.x = __builtin_amdgcn_rcpf(den.x);
                r.y = __builtin_amdgcn_rcpf(den.y);
                acc[q] = pk_fma(num, r, acc[q]);
            }
        }

        // ALL teams write partials (combine is fused into softmax, R14)
        {
            float* dst = sP + g * 4 * K_;
#pragma unroll
            for (int q = 0; q < 4; ++q)
                *(v2f*)&dst[q * K_ + k2] = acc[q];
        }
    }
    __syncthreads();

    // ---- Phase 2: fused combine + softmax, wave w (w<4) -> q row w
    if (t < 256) {
        const int lane = t & 63;
        const int q = t >> 6;
        float sv[8];
        float m = -INFINITY;
#pragma unroll
        for (int j = 0; j < 8; ++j) {
            const int idx = q * K_ + lane + 64 * j;
            float p01 = sP[idx] + sP[4 * K_ + idx];
            float p23 = sP[8 * K_ + idx] + sP[12 * K_ + idx];
            sv[j] = -2.0f * (p01 + p23);
            m = fmaxf(m, sv[j]);
        }
#pragma unroll
        for (int off = 32; off >= 1; off >>= 1) m = fmaxf(m, __shfl_xor(m, off));
        float sum = 0.f;
#pragma unroll
        for (int j = 0; j < 8; ++j) {
            sv[j] = __builtin_amdgcn_exp2f((sv[j] - m) * LOG2E);
            sum += sv[j];
        }
#pragma unroll
        for (int off = 32; off >= 1; off >>= 1) sum += __shfl_xor(sum, off);
        float rs = 1.0f / sum;
#pragma unroll
        for (int j = 0; j < 8; ++j) sS[q * K_ + lane + 64 * j] = sv[j] * rs;
    }

    // ---- Phase 3 setup: issue first V row pair BEFORE the softmax barrier
    const int h4 = (t & 63) * 4;     // h-quad owned by this thread
    const int kq = t >> 6;           // k-16th: 32 k
    const int kbeg = kq * 32;
    const float* vb = values + (long)b * K_ * H_ + h4;

    v4f va = *(const v4f*)&vb[(kbeg + 0) * H_];
    v4f vc = *(const v4f*)&vb[(kbeg + 1) * H_];

    __syncthreads();                 // sS (softmaxed weights) ready

    // ---- Phase 3: attn @ V. thread = (h-quad, k-16th); all 4 q per thread
    {
        v4f acc0 = {0.f,0.f,0.f,0.f}, acc1 = {0.f,0.f,0.f,0.f};
        v4f acc2 = {0.f,0.f,0.f,0.f}, acc3 = {0.f,0.f,0.f,0.f};
#pragma unroll 1
        for (int k = kbeg; k < kbeg + 32; k += 4) {
            // rows k,k+1 live in va,vc; prefetch rows k+2,k+3 (always valid)
            v4f vd = *(const v4f*)&vb[(k + 2) * H_];
            v4f ve = *(const v4f*)&vb[(k + 3) * H_];
            {
                v2f a0 = *(const v2f*)&sS[0 * K_ + k];  // wave-uniform bcast
                v2f a1 = *(const v2f*)&sS[1 * K_ + k];
                v2f a2 = *(const v2f*)&sS[2 * K_ + k];
                v2f a3 = *(const v2f*)&sS[3 * K_ + k];
                acc0 = pk4_fma_l(a0, va, pk4_fma_h(a0, vc, acc0));
                acc1 = pk4_fma_l(a1, va, pk4_fma_h(a1, vc, acc1));
                acc2 = pk4_fma_l(a2, va, pk4_fma_h(a2, vc, acc2));
                acc3 = pk4_fma_l(a3, va, pk4_fma_h(a3, vc, acc3));
            }
            // rows k+2,k+3 in vd,ve; prefetch next iter's k+4,k+5 into va,vc
            if (k + 4 < kbeg + 32) {     // runtime guard
                va = *(const v4f*)&vb[(k + 4) * H_];
                vc = *(const v4f*)&vb[(k + 5) * H_];
            }
            {
                v2f a0 = *(const v2f*)&sS[0 * K_ + k + 2];
                v2f a1 = *(const v2f*)&sS[1 * K_ + k + 2];
                v2f a2 = *(const v2f*)&sS[2 * K_ + k + 2];
                v2f a3 = *(const v2f*)&sS[3 * K_ + k + 2];
                acc0 = pk4_fma_l(a0, vd, pk4_fma_h(a0, ve, acc0));
                acc1 = pk4_fma_l(a1, vd, pk4_fma_h(a1, ve, acc1));
                acc2 = pk4_fma_l(a2, vd, pk4_fma_h(a2, ve, acc2));
                acc3 = pk4_fma_l(a3, vd, pk4_fma_h(a3, ve, acc3));
            }
        }

        __syncthreads();   // all sS reads done; smem becomes sRed[16][4][256]
        float* sRed = smem;
        *(v4f*)&sRed[(kq * 4 + 0) * 256 + h4] = acc0;
        *(v4f*)&sRed[(kq * 4 + 1) * 256 + h4] = acc1;
        *(v4f*)&sRed[(kq * 4 + 2) * 256 + h4] = acc2;
        *(v4f*)&sRed[(kq * 4 + 3) * 256 + h4] = acc3;
        __syncthreads();

        // final reduce: thread t -> output (q = t>>8, h = t&255), 4-way ILP
        const int q = t >> 8;
        const int h = t & 255;
        float s0 = 0.f, s1 = 0.f, s2 = 0.f, s3 = 0.f;
#pragma unroll
        for (int kk = 0; kk < 16; kk += 4) {
            s0 += sRed[((kk + 0) * 4 + q) * 256 + h];
            s1 += sRed[((kk + 1) * 4 + q) * 256 + h];
            s2 += sRed[((kk + 2) * 4 + q) * 256 + h];
            s3 += sRed[((kk + 3) * 4 + q) * 256 + h];
        }
        out[((long)(b * Q_ + q0 + q)) * H_ + h] = (s0 + s1) + (s2 + s3);
    }
}

extern "C" void kernel_launch(void* const* d_in, const int* in_sizes, int n_in,
                              void* d_out, int out_size, void* d_ws, size_t ws_size,
                              hipStream_t stream) {
    const float* queries = (const float*)d_in[0];  // [B,Q,H]
    const float* keys    = (const float*)d_in[1];  // [B,K,H]
    const float* values  = (const float*)d_in[2];  // [B,K,H]
    const float* Wq      = (const float*)d_in[3];  // [H,H]
    const float* Wk      = (const float*)d_in[4];  // [H,H]
    const float* wv      = (const float*)d_in[5];  // [H]
    float* out = (float*)d_out;

    // ws: [qe 2MB][ke 2MB]
    float* qe = (float*)d_ws;
    float* ke = qe + QE_ELEMS;

    proj_exp<<<256, 1024, 0, stream>>>(queries, keys, Wq, Wk, qe, ke);
    attn<<<512, 1024, 0, stream>>>(qe, ke, values, wv, out);
}